// Round 8
// baseline (353.161 us; speedup 1.0000x reference)
//
#include <hip/hip_runtime.h>
#include <hip/hip_bf16.h>

// ---------------------------------------------------------------------------
// Fused XCiT-style channel attention, one batch item per 512-thread block.
// B=2048, N=49 (7x7), DIM=384, HEADS=8, HD=48.
// R8: R7 structure (76.8KB LDS, 2 blocks/CU, 3-pass QKV, shfl-transpose gram)
// with the register-pressure spill killed:
//  - biases folded into a 13th MFMA k-step (X col384=1.0, W chunk k0=bias)
//  - L2 norm deferred past the gram (raw-fragment gram, epilogue scaled by
//    invQ[c]*invK[d]); accumulators stay read-only in AGPRs -> no spill.
// ---------------------------------------------------------------------------

typedef __attribute__((ext_vector_type(8))) short short8;   // 8 x bf16 (4 VGPR)
typedef __attribute__((ext_vector_type(4))) short short4v;  // 4 x bf16 (8B)
typedef __attribute__((ext_vector_type(4))) float f32x4;    // MFMA acc

#define NPOS   49
#define DIMC   384
#define SCALE_QK 0.14433756729740643f   // 48^-0.5

// LDS: two 38416B regions. A: X bf16 [49][392] -> E bf16 [8][48][48] ->
// O/relu bf16 [49][392]. B: Vn bf16 [49][392] ([pos][ch], stride 784B).
#define REGA 0
#define REGB 38416
#define LDS_BYTES 76832

// per-gemm permuted-W block: 24 nt * 13 ks * 512 lane-slots
#define WBLK 159744

__device__ __forceinline__ unsigned short f2bf(float f) {
  __hip_bfloat16 h = __float2bfloat16(f);
  unsigned short u;
  __builtin_memcpy(&u, &h, 2);
  return u;
}
__device__ __forceinline__ float bf2f(unsigned short u) {
  union { unsigned u; float f; } v; v.u = ((unsigned)u) << 16;
  return v.f;
}

// ---- prologue: permute Wq,Wk,Wv,Wp (f32 [384][384]) + biases into
// lane-ordered bf16 fragment chunks (13 k-steps; ks=12 is the bias step:
// B[k=0][n]=bias[n], B[k>0][n]=0).
// dst[((g*24+nt)*13+ks)*512 + l*8 + j]:
//   ks<12 : bf16( Wg[nt*16 + (l&15)][ks*32 + (l>>4)*8 + j] )
//   ks==12: (l>>4)==0 && j==0 ? bf16(bias_g[nt*16+(l&15)]) : 0
__global__ void wconv_kernel(const float* __restrict__ Wq, const float* __restrict__ Wk,
                             const float* __restrict__ Wv, const float* __restrict__ Wp,
                             const float* __restrict__ bq, const float* __restrict__ bk,
                             const float* __restrict__ bv, const float* __restrict__ bp,
                             unsigned short* __restrict__ dst) {
  int t = blockIdx.x * 256 + threadIdx.x;
  if (t >= 79872) return;            // 4 gemms * 24 nt * 13 ks * 64 lanes
  int l = t & 63;
  int u = t >> 6;
  int ks = u % 13; u /= 13;
  int nt = u % 24;
  int g  = u / 24;
  const float* W  = (g == 0) ? Wq : (g == 1) ? Wk : (g == 2) ? Wv : Wp;
  const float* bb = (g == 0) ? bq : (g == 1) ? bk : (g == 2) ? bv : bp;
  int row = nt * 16 + (l & 15);
  short8 o8 = {0,0,0,0,0,0,0,0};
  if (ks < 12) {
    const float* sp = W + row * 384 + ks * 32 + (l >> 4) * 8;
    #pragma unroll
    for (int j = 0; j < 8; ++j) o8[j] = (short)f2bf(sp[j]);
  } else if ((l >> 4) == 0) {
    o8[0] = (short)f2bf(bb[row]);
  }
  *(short8*)(dst + (size_t)t * 8) = o8;
}

// 4-lane transpose of the RAW (biased, unnormalized) D-fragment into gram
// A/B-fragments (pos = ks*32 + lhi*8 + j), plus per-channel inverse L2 norm
// scv[n] = 1/max(|col|,eps) computed read-only from the f32 accumulator.
__device__ __forceinline__ void xpose_raw(const f32x4 (&acc)[4][3],
                                          int lhi, int llo,
                                          short8 (&fr)[3][2], float (&scv)[3]) {
  #pragma unroll
  for (int n = 0; n < 3; ++n) {
    float ss = 0.f;
    #pragma unroll
    for (int m = 0; m < 4; ++m)
      #pragma unroll
      for (int r = 0; r < 4; ++r) {
        int np = m * 16 + lhi * 4 + r;
        float v = acc[m][n][r];
        if (np < 49) ss += v * v;
      }
    ss += __shfl_xor(ss, 16, 64);
    ss += __shfl_xor(ss, 32, 64);
    scv[n] = 1.f / fmaxf(sqrtf(ss), 1e-12f);
    const int src_lo = llo + ((lhi & 1) << 5);
    const int src_hi = src_lo + 16;
    #pragma unroll
    for (int m = 0; m < 4; ++m) {
      unsigned p0 = (unsigned)f2bf(acc[m][n][0]) | ((unsigned)f2bf(acc[m][n][1]) << 16);
      unsigned p1 = (unsigned)f2bf(acc[m][n][2]) | ((unsigned)f2bf(acc[m][n][3]) << 16);
      int lo0 = __shfl((int)p0, src_lo, 64);
      int lo1 = __shfl((int)p1, src_lo, 64);
      int hi0 = __shfl((int)p0, src_hi, 64);
      int hi1 = __shfl((int)p1, src_hi, 64);
      if ((lhi >> 1) == (m & 1)) {
        union { int i[4]; short8 s; } u;
        u.i[0] = lo0; u.i[1] = lo1; u.i[2] = hi0; u.i[3] = hi1;
        fr[n][m >> 1] = u.s;
      }
    }
    // zero pos>=49 in the ks=1 fragment (lhi==2: keep pos48 only; lhi==3: all pad)
    if (lhi == 2) {
      union { int i[4]; short8 s; } u; u.s = fr[n][1];
      u.i[0] &= 0xFFFF; u.i[1] = 0; u.i[2] = 0; u.i[3] = 0;
      fr[n][1] = u.s;
    } else if (lhi == 3) {
      short8 z = {0,0,0,0,0,0,0,0};
      fr[n][1] = z;
    }
  }
}

// ---- main fused kernel -----------------------------------------------------
__global__ __launch_bounds__(512, 4) void attn_fused_kernel(
    const float* __restrict__ x,
    const float* __restrict__ Wvl, const float* __restrict__ bvl,
    const float* __restrict__ Wth1, const float* __restrict__ bth1,
    const float* __restrict__ Wth2, const float* __restrict__ bth2,
    const unsigned short* __restrict__ Wbf,
    float* __restrict__ out) {
  extern __shared__ char smem[];
  const int tid = threadIdx.x;
  const int l   = tid & 63;
  const int w   = tid >> 6;          // wave 0..7 == head h
  const int lhi = l >> 4;            // 0..3
  const int llo = l & 15;
  const int b   = blockIdx.x;

  const float* xb = x + (size_t)b * (NPOS * DIMC);
  const unsigned short* Wq_p = Wbf;
  const unsigned short* Wk_p = Wbf + WBLK;
  const unsigned short* Wv_p = Wbf + 2 * WBLK;
  const unsigned short* Wp_p = Wbf + 3 * WBLK;

  // ---- phase 0: stage x_b -> X bf16 [49][392]; ones-column at col 384 -------
  for (int idx = tid; idx < 49 * 48; idx += 512) {
    int row = idx / 48, c8 = idx % 48;
    const float4 v0 = *(const float4*)(xb + row * 384 + c8 * 8);
    const float4 v1 = *(const float4*)(xb + row * 384 + c8 * 8 + 4);
    short8 s;
    s[0] = (short)f2bf(v0.x); s[1] = (short)f2bf(v0.y);
    s[2] = (short)f2bf(v0.z); s[3] = (short)f2bf(v0.w);
    s[4] = (short)f2bf(v1.x); s[5] = (short)f2bf(v1.y);
    s[6] = (short)f2bf(v1.z); s[7] = (short)f2bf(v1.w);
    *(short8*)(smem + REGA + row * 784 + c8 * 16) = s;
  }
  if (tid < 49) {                    // cols 384..391 = {1, 0 x7}
    short8 u1 = {0,0,0,0,0,0,0,0};
    u1[0] = (short)f2bf(1.0f);
    *(short8*)(smem + REGA + tid * 784 + 768) = u1;
  }
  if (tid >= 64 && tid < 68) {       // zero REGB[0..63]: ks=12 row-48 A-read
    short8 z = {0,0,0,0,0,0,0,0};    // overruns into here; weights are 0 but
    *(short8*)(smem + REGB + (tid - 64) * 16) = z;   // dirty-LDS NaN*0=NaN.
  }
  __syncthreads();   // b1

  // ---- V GEMM pass FIRST (aV dies before qf/kf live); 13 k-steps ------------
  {
    f32x4 aV[4][3] = {};
    for (int ks = 0; ks < 13; ++ks) {
      short8 a[4];
      #pragma unroll
      for (int m = 0; m < 4; ++m) {
        int row = m * 16 + llo; row = (row > 48) ? 48 : row;   // M-pad clamp
        a[m] = *(const short8*)(smem + REGA + row * 784 + ks * 64 + lhi * 16);
      }
      #pragma unroll
      for (int n = 0; n < 3; ++n) {
        const int nt = w * 3 + n;
        short8 bv8 = *(const short8*)(Wv_p + ((nt * 13 + ks) << 9) + (l << 3));
        #pragma unroll
        for (int m = 0; m < 4; ++m)
          aV[m][n] = __builtin_amdgcn_mfma_f32_16x16x32_bf16(a[m], bv8, aV[m][n], 0, 0, 0);
      }
    }
    #pragma unroll
    for (int n = 0; n < 3; ++n) {
      const int o = (w * 3 + n) * 16 + llo;
      #pragma unroll
      for (int m = 0; m < 4; ++m)
        #pragma unroll
        for (int r = 0; r < 4; ++r) {
          int np = m * 16 + lhi * 4 + r;
          if (np < 49)
            *(unsigned short*)(smem + REGB + np * 784 + o * 2) = f2bf(aV[m][n][r]);
        }
    }
  }

  short8 qf[3][2], kf[3][2];
  float qsc[3], ksc[3];
  // ---- Q GEMM pass -> raw qf + inv norms ------------------------------------
  {
    f32x4 aQ[4][3] = {};
    for (int ks = 0; ks < 13; ++ks) {
      short8 a[4];
      #pragma unroll
      for (int m = 0; m < 4; ++m) {
        int row = m * 16 + llo; row = (row > 48) ? 48 : row;
        a[m] = *(const short8*)(smem + REGA + row * 784 + ks * 64 + lhi * 16);
      }
      #pragma unroll
      for (int n = 0; n < 3; ++n) {
        const int nt = w * 3 + n;
        short8 bq8 = *(const short8*)(Wq_p + ((nt * 13 + ks) << 9) + (l << 3));
        #pragma unroll
        for (int m = 0; m < 4; ++m)
          aQ[m][n] = __builtin_amdgcn_mfma_f32_16x16x32_bf16(a[m], bq8, aQ[m][n], 0, 0, 0);
      }
    }
    xpose_raw(aQ, lhi, llo, qf, qsc);   // aQ dies (read-only throughout)
  }

  // ---- K GEMM pass -> raw kf + inv norms ------------------------------------
  {
    f32x4 aK[4][3] = {};
    for (int ks = 0; ks < 13; ++ks) {
      short8 a[4];
      #pragma unroll
      for (int m = 0; m < 4; ++m) {
        int row = m * 16 + llo; row = (row > 48) ? 48 : row;
        a[m] = *(const short8*)(smem + REGA + row * 784 + ks * 64 + lhi * 16);
      }
      #pragma unroll
      for (int n = 0; n < 3; ++n) {
        const int nt = w * 3 + n;
        short8 bk8 = *(const short8*)(Wk_p + ((nt * 13 + ks) << 9) + (l << 3));
        #pragma unroll
        for (int m = 0; m < 4; ++m)
          aK[m][n] = __builtin_amdgcn_mfma_f32_16x16x32_bf16(a[m], bk8, aK[m][n], 0, 0, 0);
      }
    }
    xpose_raw(aK, lhi, llo, kf, ksc);   // aK dies
  }

  // ---- raw gram (pure registers) --------------------------------------------
  f32x4 g[3][3] = {};
  #pragma unroll
  for (int ks = 0; ks < 2; ++ks)
    #pragma unroll
    for (int mt = 0; mt < 3; ++mt)
      #pragma unroll
      for (int dt = 0; dt < 3; ++dt)
        g[mt][dt] = __builtin_amdgcn_mfma_f32_16x16x32_bf16(qf[mt][ks], kf[dt][ks], g[mt][dt], 0, 0, 0);

  // gather invQ[c] for this lane's 12 output rows (c = mt*16 + lhi*4 + r)
  float invQv[3][4];
  #pragma unroll
  for (int mt = 0; mt < 3; ++mt)
    #pragma unroll
    for (int r = 0; r < 4; ++r)
      invQv[mt][r] = __shfl(qsc[mt], lhi * 4 + r, 64);

  __syncthreads();   // b2: all waves done reading X; region A reusable as E

  // ---- E store: normalized gram [8][48][48] bf16 at region A ----------------
  #pragma unroll
  for (int mt = 0; mt < 3; ++mt)
    #pragma unroll
    for (int dt = 0; dt < 3; ++dt)
      #pragma unroll
      for (int r = 0; r < 4; ++r) {
        int c = mt * 16 + lhi * 4 + r, d = dt * 16 + llo;
        float val = g[mt][dt][r] * invQv[mt][r] * ksc[dt];
        *(unsigned short*)(smem + REGA + ((w * 48 + c) * 48 + d) * 2) = f2bf(val);
      }
  __syncthreads();   // b3

  // ---- talking-heads mix1 (SCALE folded into W1), in-place on E -------------
  {
    float w1[64], b1r[8];
    #pragma unroll
    for (int i = 0; i < 64; ++i) w1[i] = Wth1[i] * SCALE_QK;
    #pragma unroll
    for (int i = 0; i < 8; ++i) b1r[i] = bth1[i];
    for (int s = tid; s < 2304; s += 512) {
      char* base = smem + REGA + s * 2;   // s = c*48+d
      float gg[8];
      #pragma unroll
      for (int hh = 0; hh < 8; ++hh) gg[hh] = bf2f(*(unsigned short*)(base + hh * 4608));
      #pragma unroll
      for (int gdx = 0; gdx < 8; ++gdx) {
        float t = b1r[gdx];
        #pragma unroll
        for (int hh = 0; hh < 8; ++hh) t += gg[hh] * w1[gdx * 8 + hh];
        *(unsigned short*)(base + gdx * 4608) = f2bf(t);
      }
    }
  }
  __syncthreads();   // b4

  // ---- row softmax over d (rows = (g,c), 384 of them) -----------------------
  for (int row = tid; row < 384; row += 512) {
    char* rp = smem + REGA + row * 96;
    float vv[48];
    #pragma unroll
    for (int i = 0; i < 6; ++i) {
      short8 v8 = *(short8*)(rp + i * 16);
      #pragma unroll
      for (int j = 0; j < 8; ++j) vv[i * 8 + j] = bf2f((unsigned short)v8[j]);
    }
    float mx = vv[0];
    #pragma unroll
    for (int i = 1; i < 48; ++i) mx = fmaxf(mx, vv[i]);
    float sum = 0.f;
    #pragma unroll
    for (int i = 0; i < 48; ++i) { vv[i] = __expf(vv[i] - mx); sum += vv[i]; }
    float inv = 1.f / sum;
    #pragma unroll
    for (int i = 0; i < 6; ++i) {
      short8 o8;
      #pragma unroll
      for (int j = 0; j < 8; ++j) o8[j] = (short)f2bf(vv[i * 8 + j] * inv);
      *(short8*)(rp + i * 16) = o8;
    }
  }
  __syncthreads();   // b5

  // ---- talking-heads mix2, in-place on E ------------------------------------
  {
    float w2[64], b2r[8];
    #pragma unroll
    for (int i = 0; i < 64; ++i) w2[i] = Wth2[i];
    #pragma unroll
    for (int i = 0; i < 8; ++i) b2r[i] = bth2[i];
    for (int s = tid; s < 2304; s += 512) {
      char* base = smem + REGA + s * 2;
      float gg[8];
      #pragma unroll
      for (int hh = 0; hh < 8; ++hh) gg[hh] = bf2f(*(unsigned short*)(base + hh * 4608));
      #pragma unroll
      for (int gdx = 0; gdx < 8; ++gdx) {
        float t = b2r[gdx];
        #pragma unroll
        for (int hh = 0; hh < 8; ++hh) t += gg[hh] * w2[gdx * 8 + hh];
        *(unsigned short*)(base + gdx * 4608) = f2bf(t);
      }
    }
  }
  __syncthreads();   // b6

  // ---- AV per head (head = w): A = E rows, B = Vn ---------------------------
  f32x4 oacc[3][4] = {};
  {
    #pragma unroll
    for (int ks = 0; ks < 2; ++ks) {
      short8 af[3];
      #pragma unroll
      for (int m = 0; m < 3; ++m) {
        short8 t = {0,0,0,0,0,0,0,0};
        if (!(ks == 1 && lhi >= 2))   // d >= 48 is K-pad
          t = *(const short8*)(smem + REGA + (w * 48 + m * 16 + llo) * 96 + ks * 64 + lhi * 16);
        af[m] = t;
      }
      #pragma unroll
      for (int nt = 0; nt < 4; ++nt) {
        int n = nt * 16 + llo; int nc = (n > 48) ? 48 : n;   // pos clamp
        short8 bf8 = {0,0,0,0,0,0,0,0};
        if (!(ks == 1 && lhi >= 2))   // matching mask (unwritten Vn pads)
          bf8 = *(const short8*)(smem + REGB + nc * 784 + w * 96 + ks * 64 + lhi * 16);
        #pragma unroll
        for (int m = 0; m < 3; ++m)
          oacc[m][nt] = __builtin_amdgcn_mfma_f32_16x16x32_bf16(af[m], bf8, oacc[m][nt], 0, 0, 0);
      }
    }
  }
  __syncthreads();   // b7: all E reads done; region A reusable as O/relu buf

  // ---- O store (attn*V, pre-vlocal, pre-relu) -> region A [pos][ch] ---------
  #pragma unroll
  for (int m = 0; m < 3; ++m)
    #pragma unroll
    for (int nt = 0; nt < 4; ++nt) {
      const int n = nt * 16 + llo;
      if (n >= 49) continue;
      const int o0 = w * 48 + m * 16 + lhi * 4;
      short4v ot;
      #pragma unroll
      for (int r = 0; r < 4; ++r) ot[r] = (short)f2bf(oacc[m][nt][r]);
      *(short4v*)(smem + REGA + n * 784 + o0 * 2) = ot;
    }
  __syncthreads();   // b8

  // ---- depthwise 3x3 on Vn + bvl + O, ReLU -> region A; restore ones-col ----
  for (int idx = tid; idx < 2352; idx += 512) {
    int n = idx / 48, c8 = idx % 48;
    int o0 = c8 * 8;
    int y = n / 7, xq = n % 7;
    float a[8];
    #pragma unroll
    for (int j = 0; j < 8; ++j) a[j] = bvl[o0 + j];
    #pragma unroll
    for (int dy = 0; dy < 3; ++dy) {
      int yy = y + dy - 1;
      if (yy < 0 || yy > 6) continue;
      #pragma unroll
      for (int dx = 0; dx < 3; ++dx) {
        int xx = xq + dx - 1;
        if (xx < 0 || xx > 6) continue;
        short8 vv = *(const short8*)(smem + REGB + (yy * 7 + xx) * 784 + o0 * 2);
        const float* wp = Wvl + (dy * 3 + dx) * 384 + o0;
        #pragma unroll
        for (int j = 0; j < 8; ++j) a[j] += bf2f((unsigned short)vv[j]) * wp[j];
      }
    }
    char* p = smem + REGA + n * 784 + o0 * 2;
    short8 oc = *(short8*)p;
    short8 s8;
    #pragma unroll
    for (int j = 0; j < 8; ++j)
      s8[j] = (short)f2bf(fmaxf(bf2f((unsigned short)oc[j]) + a[j], 0.f));
    *(short8*)p = s8;
  }
  if (tid < 49) {                    // E overlay clobbered col 384; restore 1.0
    short8 u1 = {0,0,0,0,0,0,0,0};
    u1[0] = (short)f2bf(1.0f);
    *(short8*)(smem + REGA + tid * 784 + 768) = u1;
  }
  __syncthreads();   // b9

  // ---- P GEMM: out = relu_buf @ Wp^T (+bp via k-step 12) --------------------
  {
    f32x4 acc[4][3] = {};
    for (int ks = 0; ks < 13; ++ks) {
      short8 a[4];
      #pragma unroll
      for (int m = 0; m < 4; ++m) {
        int row = m * 16 + llo; row = (row > 48) ? 48 : row;
        a[m] = *(const short8*)(smem + REGA + row * 784 + ks * 64 + lhi * 16);
      }
      #pragma unroll
      for (int n = 0; n < 3; ++n) {
        const int nt = w * 3 + n;
        short8 bfr = *(const short8*)(Wp_p + ((nt * 13 + ks) << 9) + (l << 3));
        #pragma unroll
        for (int m = 0; m < 4; ++m)
          acc[m][n] = __builtin_amdgcn_mfma_f32_16x16x32_bf16(a[m], bfr, acc[m][n], 0, 0, 0);
      }
    }
    float* ob = out + (size_t)b * (NPOS * DIMC);
    #pragma unroll
    for (int n = 0; n < 3; ++n) {
      const int o = (w * 3 + n) * 16 + llo;
      #pragma unroll
      for (int m = 0; m < 4; ++m)
        #pragma unroll
        for (int r = 0; r < 4; ++r) {
          int np = m * 16 + lhi * 4 + r;
          if (np < 49) ob[np * 384 + o] = acc[m][n][r];
        }
    }
  }
}

extern "C" void kernel_launch(void* const* d_in, const int* in_sizes, int n_in,
                              void* d_out, int out_size, void* d_ws, size_t ws_size,
                              hipStream_t stream) {
  const float* x    = (const float*)d_in[0];
  const float* Wq   = (const float*)d_in[1];
  const float* bq   = (const float*)d_in[2];
  const float* Wk   = (const float*)d_in[3];
  const float* bk   = (const float*)d_in[4];
  const float* Wv   = (const float*)d_in[5];
  const float* bv   = (const float*)d_in[6];
  const float* Wvl  = (const float*)d_in[7];
  const float* bvl  = (const float*)d_in[8];
  const float* Wth1 = (const float*)d_in[9];
  const float* bth1 = (const float*)d_in[10];
  const float* Wth2 = (const float*)d_in[11];
  const float* bth2 = (const float*)d_in[12];
  const float* Wp   = (const float*)d_in[13];
  const float* bp   = (const float*)d_in[14];
  unsigned short* Wbf = (unsigned short*)d_ws;   // 1.25 MB of scratch used
  float* out = (float*)d_out;

  hipLaunchKernelGGL(wconv_kernel, dim3(312), dim3(256), 0, stream,
                     Wq, Wk, Wv, Wp, bq, bk, bv, bp, Wbf);
  hipLaunchKernelGGL(attn_fused_kernel, dim3(2048), dim3(512), LDS_BYTES, stream,
                     x, Wvl, bvl, Wth1, bth1, Wth2, bth2, Wbf, out);
}

// Round 9
// 292.873 us; speedup vs baseline: 1.2059x; 1.2059x over previous
//
#include <hip/hip_runtime.h>
#include <hip/hip_bf16.h>

// ---------------------------------------------------------------------------
// Fused XCiT-style channel attention, one batch item per 512-thread block.
// B=2048, N=49 (7x7), DIM=384, HEADS=8, HD=48.
// R9: fit the 128-unified-reg/wave cap that launch_bounds(512,4) implies
// (512-reg pool / 4 waves/SIMD). QKV GEMMs split into per-n-tile bodies
// (16-reg acc, static-n macro instantiation, compiler memory fences to
// block LDS-load CSE); talking-head weights cached in LDS (broadcast
// reads) instead of 144 f32 registers. Structure otherwise = R8.
// ---------------------------------------------------------------------------

typedef __attribute__((ext_vector_type(8))) short short8;   // 8 x bf16 (4 VGPR)
typedef __attribute__((ext_vector_type(4))) short short4v;  // 4 x bf16 (8B)
typedef __attribute__((ext_vector_type(4))) float f32x4;    // MFMA acc

#define NPOS   49
#define DIMC   384
#define SCALE_QK 0.14433756729740643f   // 48^-0.5

// LDS: two 38416B regions. A: X bf16 [49][392] -> E bf16 [8][48][48] (+weight
// cache in the 1552B slack) -> O/relu bf16 [49][392]. B: Vn bf16 [49][392].
#define REGA 0
#define REGB 38416
#define WOFF 36864            // weight cache: 64f32 w1, 8 b1, 64 w2, 8 b2
#define LDS_BYTES 76832

// per-gemm permuted-W block: 24 nt * 13 ks * 512 lane-slots
#define WBLK 159744

__device__ __forceinline__ unsigned short f2bf(float f) {
  __hip_bfloat16 h = __float2bfloat16(f);
  unsigned short u;
  __builtin_memcpy(&u, &h, 2);
  return u;
}
__device__ __forceinline__ float bf2f(unsigned short u) {
  union { unsigned u; float f; } v; v.u = ((unsigned)u) << 16;
  return v.f;
}

// ---- prologue: permute Wq,Wk,Wv,Wp + biases into lane-ordered bf16 chunks
// (13 k-steps; ks=12 is the bias step: B[k=0][n]=bias[n], else 0).
__global__ void wconv_kernel(const float* __restrict__ Wq, const float* __restrict__ Wk,
                             const float* __restrict__ Wv, const float* __restrict__ Wp,
                             const float* __restrict__ bq, const float* __restrict__ bk,
                             const float* __restrict__ bv, const float* __restrict__ bp,
                             unsigned short* __restrict__ dst) {
  int t = blockIdx.x * 256 + threadIdx.x;
  if (t >= 79872) return;            // 4 gemms * 24 nt * 13 ks * 64 lanes
  int l = t & 63;
  int u = t >> 6;
  int ks = u % 13; u /= 13;
  int nt = u % 24;
  int g  = u / 24;
  const float* W  = (g == 0) ? Wq : (g == 1) ? Wk : (g == 2) ? Wv : Wp;
  const float* bb = (g == 0) ? bq : (g == 1) ? bk : (g == 2) ? bv : bp;
  int row = nt * 16 + (l & 15);
  short8 o8 = {0,0,0,0,0,0,0,0};
  if (ks < 12) {
    const float* sp = W + row * 384 + ks * 32 + (l >> 4) * 8;
    #pragma unroll
    for (int j = 0; j < 8; ++j) o8[j] = (short)f2bf(sp[j]);
  } else if ((l >> 4) == 0) {
    o8[0] = (short)f2bf(bb[row]);
  }
  *(short8*)(dst + (size_t)t * 8) = o8;
}

// 4-lane transpose of one RAW n-tile D-fragment into gram A/B fragments
// (pos = ks*32 + lhi*8 + j), plus per-channel inverse L2 norm (read-only acc).
__device__ __forceinline__ void xpose_n(const f32x4 (&acc)[4],
                                        int lhi, int llo,
                                        short8 (&fr)[2], float& sc) {
  float ss = 0.f;
  #pragma unroll
  for (int m = 0; m < 4; ++m)
    #pragma unroll
    for (int r = 0; r < 4; ++r) {
      int np = m * 16 + lhi * 4 + r;
      float v = acc[m][r];
      if (np < 49) ss += v * v;
    }
  ss += __shfl_xor(ss, 16, 64);
  ss += __shfl_xor(ss, 32, 64);
  sc = 1.f / fmaxf(sqrtf(ss), 1e-12f);
  const int src_lo = llo + ((lhi & 1) << 5);
  const int src_hi = src_lo + 16;
  #pragma unroll
  for (int m = 0; m < 4; ++m) {
    unsigned p0 = (unsigned)f2bf(acc[m][0]) | ((unsigned)f2bf(acc[m][1]) << 16);
    unsigned p1 = (unsigned)f2bf(acc[m][2]) | ((unsigned)f2bf(acc[m][3]) << 16);
    int lo0 = __shfl((int)p0, src_lo, 64);
    int lo1 = __shfl((int)p1, src_lo, 64);
    int hi0 = __shfl((int)p0, src_hi, 64);
    int hi1 = __shfl((int)p1, src_hi, 64);
    if ((lhi >> 1) == (m & 1)) {
      union { int i[4]; short8 s; } u;
      u.i[0] = lo0; u.i[1] = lo1; u.i[2] = hi0; u.i[3] = hi1;
      fr[m >> 1] = u.s;
    }
  }
  // zero pos>=49 in the ks=1 fragment (lhi==2: keep pos48; lhi==3: all pad)
  if (lhi == 2) {
    union { int i[4]; short8 s; } u; u.s = fr[1];
    u.i[0] &= 0xFFFF; u.i[1] = 0; u.i[2] = 0; u.i[3] = 0;
    fr[1] = u.s;
  } else if (lhi == 3) {
    short8 z = {0,0,0,0,0,0,0,0};
    fr[1] = z;
  }
}

// ---- main fused kernel -----------------------------------------------------
__global__ __launch_bounds__(512, 4) void attn_fused_kernel(
    const float* __restrict__ x,
    const float* __restrict__ Wvl, const float* __restrict__ bvl,
    const float* __restrict__ Wth1, const float* __restrict__ bth1,
    const float* __restrict__ Wth2, const float* __restrict__ bth2,
    const unsigned short* __restrict__ Wbf,
    float* __restrict__ out) {
  extern __shared__ char smem[];
  const int tid = threadIdx.x;
  const int l   = tid & 63;
  const int w   = tid >> 6;          // wave 0..7 == head h
  const int lhi = l >> 4;            // 0..3
  const int llo = l & 15;
  const int b   = blockIdx.x;

  const float* xb = x + (size_t)b * (NPOS * DIMC);
  const unsigned short* Wq_p = Wbf;
  const unsigned short* Wk_p = Wbf + WBLK;
  const unsigned short* Wv_p = Wbf + 2 * WBLK;
  const unsigned short* Wp_p = Wbf + 3 * WBLK;

  // ---- phase 0: stage x_b -> X bf16 [49][392]; ones-column at col 384 -------
  for (int idx = tid; idx < 49 * 48; idx += 512) {
    int row = idx / 48, c8 = idx % 48;
    const float4 v0 = *(const float4*)(xb + row * 384 + c8 * 8);
    const float4 v1 = *(const float4*)(xb + row * 384 + c8 * 8 + 4);
    short8 s;
    s[0] = (short)f2bf(v0.x); s[1] = (short)f2bf(v0.y);
    s[2] = (short)f2bf(v0.z); s[3] = (short)f2bf(v0.w);
    s[4] = (short)f2bf(v1.x); s[5] = (short)f2bf(v1.y);
    s[6] = (short)f2bf(v1.z); s[7] = (short)f2bf(v1.w);
    *(short8*)(smem + REGA + row * 784 + c8 * 16) = s;
  }
  if (tid < 49) {                    // cols 384..391 = {1, 0 x7}
    short8 u1 = {0,0,0,0,0,0,0,0};
    u1[0] = (short)f2bf(1.0f);
    *(short8*)(smem + REGA + tid * 784 + 768) = u1;
  }
  if (tid >= 64 && tid < 68) {       // zero REGB[0..63] (ks=12 row-48 overrun)
    short8 z = {0,0,0,0,0,0,0,0};
    *(short8*)(smem + REGB + (tid - 64) * 16) = z;
  }
  __syncthreads();   // b1

  short8 qfv[3][2], kfv[3][2];
  float  qscv[3], kscv[3];

  // One n-tile GEMM body: 13 k-steps, 16-reg accumulator. FENCE blocks
  // cross-body CSE of the A-fragment ds_reads (keeps live-set ~90 regs).
#define FENCE asm volatile("" ::: "memory")
#define GEMM_N(WPTR, NIDX, ACC)                                                \
  {                                                                            \
    for (int ks = 0; ks < 13; ++ks) {                                          \
      short8 a[4];                                                             \
      _Pragma("unroll")                                                        \
      for (int m = 0; m < 4; ++m) {                                            \
        int row = m * 16 + llo; row = (row > 48) ? 48 : row;                   \
        a[m] = *(const short8*)(smem + REGA + row * 784 + ks * 64 + lhi * 16); \
      }                                                                        \
      short8 b8 = *(const short8*)(WPTR + (((w * 3 + NIDX) * 13 + ks) << 9) + (l << 3)); \
      _Pragma("unroll")                                                        \
      for (int m = 0; m < 4; ++m)                                              \
        ACC[m] = __builtin_amdgcn_mfma_f32_16x16x32_bf16(a[m], b8, ACC[m], 0, 0, 0); \
    }                                                                          \
  }

  // ---- V pass (per n-tile; biased V -> REGB [pos][ch]) ----------------------
  #pragma unroll
  for (int n = 0; n < 3; ++n) {
    f32x4 aV[4] = {};
    GEMM_N(Wv_p, n, aV);
    const int o = (w * 3 + n) * 16 + llo;
    #pragma unroll
    for (int m = 0; m < 4; ++m)
      #pragma unroll
      for (int r = 0; r < 4; ++r) {
        int np = m * 16 + lhi * 4 + r;
        if (np < 49)
          *(unsigned short*)(smem + REGB + np * 784 + o * 2) = f2bf(aV[m][r]);
      }
    FENCE;
  }

  // ---- Q pass -> raw qf + inv norms ------------------------------------------
  {
    { f32x4 acc[4] = {}; GEMM_N(Wq_p, 0, acc); xpose_n(acc, lhi, llo, qfv[0], qscv[0]); FENCE; }
    { f32x4 acc[4] = {}; GEMM_N(Wq_p, 1, acc); xpose_n(acc, lhi, llo, qfv[1], qscv[1]); FENCE; }
    { f32x4 acc[4] = {}; GEMM_N(Wq_p, 2, acc); xpose_n(acc, lhi, llo, qfv[2], qscv[2]); FENCE; }
  }
  // ---- K pass -> raw kf + inv norms ------------------------------------------
  {
    { f32x4 acc[4] = {}; GEMM_N(Wk_p, 0, acc); xpose_n(acc, lhi, llo, kfv[0], kscv[0]); FENCE; }
    { f32x4 acc[4] = {}; GEMM_N(Wk_p, 1, acc); xpose_n(acc, lhi, llo, kfv[1], kscv[1]); FENCE; }
    { f32x4 acc[4] = {}; GEMM_N(Wk_p, 2, acc); xpose_n(acc, lhi, llo, kfv[2], kscv[2]); FENCE; }
  }

  // ---- raw gram (pure registers) --------------------------------------------
  f32x4 g[3][3] = {};
  #pragma unroll
  for (int ks = 0; ks < 2; ++ks)
    #pragma unroll
    for (int mt = 0; mt < 3; ++mt)
      #pragma unroll
      for (int dt = 0; dt < 3; ++dt)
        g[mt][dt] = __builtin_amdgcn_mfma_f32_16x16x32_bf16(qfv[mt][ks], kfv[dt][ks], g[mt][dt], 0, 0, 0);

  // gather invQ[c] for this lane's 12 output rows (c = mt*16 + lhi*4 + r)
  float invQv[3][4];
  #pragma unroll
  for (int mt = 0; mt < 3; ++mt)
    #pragma unroll
    for (int r = 0; r < 4; ++r)
      invQv[mt][r] = __shfl(qscv[mt], lhi * 4 + r, 64);

  __syncthreads();   // b2: all waves done reading X; region A reusable

  // ---- E store (normalized gram) + weight-cache fill ------------------------
  #pragma unroll
  for (int mt = 0; mt < 3; ++mt)
    #pragma unroll
    for (int dt = 0; dt < 3; ++dt)
      #pragma unroll
      for (int r = 0; r < 4; ++r) {
        int c = mt * 16 + lhi * 4 + r, d = dt * 16 + llo;
        float val = g[mt][dt][r] * invQv[mt][r] * kscv[dt];
        *(unsigned short*)(smem + REGA + ((w * 48 + c) * 48 + d) * 2) = f2bf(val);
      }
  if (tid < 64)       *(float*)(smem + WOFF + tid * 4) = Wth1[tid] * SCALE_QK;
  else if (tid < 72)  *(float*)(smem + WOFF + 256 + (tid - 64) * 4) = bth1[tid - 64];
  else if (tid < 136) *(float*)(smem + WOFF + 288 + (tid - 72) * 4) = Wth2[tid - 72];
  else if (tid < 144) *(float*)(smem + WOFF + 544 + (tid - 136) * 4) = bth2[tid - 136];
  __syncthreads();   // b3

  // ---- talking-heads mix1 (weights from LDS broadcast), in-place on E -------
  for (int s = tid; s < 2304; s += 512) {
    char* base = smem + REGA + s * 2;   // s = c*48+d
    float gg[8];
    #pragma unroll
    for (int hh = 0; hh < 8; ++hh) gg[hh] = bf2f(*(unsigned short*)(base + hh * 4608));
    #pragma unroll
    for (int gdx = 0; gdx < 8; ++gdx) {
      float t = *(const float*)(smem + WOFF + 256 + gdx * 4);
      #pragma unroll
      for (int hh = 0; hh < 8; ++hh)
        t += gg[hh] * *(const float*)(smem + WOFF + (gdx * 8 + hh) * 4);
      *(unsigned short*)(base + gdx * 4608) = f2bf(t);
    }
  }
  __syncthreads();   // b4

  // ---- row softmax over d (rows = (g,c), 384 of them) -----------------------
  for (int row = tid; row < 384; row += 512) {
    char* rp = smem + REGA + row * 96;
    float vv[48];
    #pragma unroll
    for (int i = 0; i < 6; ++i) {
      short8 v8 = *(short8*)(rp + i * 16);
      #pragma unroll
      for (int j = 0; j < 8; ++j) vv[i * 8 + j] = bf2f((unsigned short)v8[j]);
    }
    float mx = vv[0];
    #pragma unroll
    for (int i = 1; i < 48; ++i) mx = fmaxf(mx, vv[i]);
    float sum = 0.f;
    #pragma unroll
    for (int i = 0; i < 48; ++i) { vv[i] = __expf(vv[i] - mx); sum += vv[i]; }
    float inv = 1.f / sum;
    #pragma unroll
    for (int i = 0; i < 6; ++i) {
      short8 o8;
      #pragma unroll
      for (int j = 0; j < 8; ++j) o8[j] = (short)f2bf(vv[i * 8 + j] * inv);
      *(short8*)(rp + i * 16) = o8;
    }
  }
  __syncthreads();   // b5

  // ---- talking-heads mix2 (weights from LDS broadcast), in-place on E -------
  for (int s = tid; s < 2304; s += 512) {
    char* base = smem + REGA + s * 2;
    float gg[8];
    #pragma unroll
    for (int hh = 0; hh < 8; ++hh) gg[hh] = bf2f(*(unsigned short*)(base + hh * 4608));
    #pragma unroll
    for (int gdx = 0; gdx < 8; ++gdx) {
      float t = *(const float*)(smem + WOFF + 544 + gdx * 4);
      #pragma unroll
      for (int hh = 0; hh < 8; ++hh)
        t += gg[hh] * *(const float*)(smem + WOFF + 288 + (gdx * 8 + hh) * 4);
      *(unsigned short*)(base + gdx * 4608) = f2bf(t);
    }
  }
  __syncthreads();   // b6

  // ---- AV per head (head = w): A = E rows, B = Vn ---------------------------
  f32x4 oacc[3][4] = {};
  {
    #pragma unroll
    for (int ks = 0; ks < 2; ++ks) {
      short8 af[3];
      #pragma unroll
      for (int m = 0; m < 3; ++m) {
        short8 t = {0,0,0,0,0,0,0,0};
        if (!(ks == 1 && lhi >= 2))   // d >= 48 is K-pad
          t = *(const short8*)(smem + REGA + (w * 48 + m * 16 + llo) * 96 + ks * 64 + lhi * 16);
        af[m] = t;
      }
      #pragma unroll
      for (int nt = 0; nt < 4; ++nt) {
        int n = nt * 16 + llo; int nc = (n > 48) ? 48 : n;   // pos clamp
        short8 bf8 = {0,0,0,0,0,0,0,0};
        if (!(ks == 1 && lhi >= 2))   // matching mask (unwritten Vn pads)
          bf8 = *(const short8*)(smem + REGB + nc * 784 + w * 96 + ks * 64 + lhi * 16);
        #pragma unroll
        for (int m = 0; m < 3; ++m)
          oacc[m][nt] = __builtin_amdgcn_mfma_f32_16x16x32_bf16(af[m], bf8, oacc[m][nt], 0, 0, 0);
      }
    }
  }
  __syncthreads();   // b7: all E reads done; region A reusable as O/relu buf

  // ---- O store (attn*V, pre-vlocal, pre-relu) -> region A [pos][ch] ---------
  #pragma unroll
  for (int m = 0; m < 3; ++m)
    #pragma unroll
    for (int nt = 0; nt < 4; ++nt) {
      const int n = nt * 16 + llo;
      if (n >= 49) continue;
      const int o0 = w * 48 + m * 16 + lhi * 4;
      short4v ot;
      #pragma unroll
      for (int r = 0; r < 4; ++r) ot[r] = (short)f2bf(oacc[m][nt][r]);
      *(short4v*)(smem + REGA + n * 784 + o0 * 2) = ot;
    }
  __syncthreads();   // b8

  // ---- depthwise 3x3 on Vn + bvl + O, ReLU -> region A; restore ones-col ----
  for (int idx = tid; idx < 2352; idx += 512) {
    int n = idx / 48, c8 = idx % 48;
    int o0 = c8 * 8;
    int y = n / 7, xq = n % 7;
    float a[8];
    #pragma unroll
    for (int j = 0; j < 8; ++j) a[j] = bvl[o0 + j];
    #pragma unroll
    for (int dy = 0; dy < 3; ++dy) {
      int yy = y + dy - 1;
      if (yy < 0 || yy > 6) continue;
      #pragma unroll
      for (int dx = 0; dx < 3; ++dx) {
        int xx = xq + dx - 1;
        if (xx < 0 || xx > 6) continue;
        short8 vv = *(const short8*)(smem + REGB + (yy * 7 + xx) * 784 + o0 * 2);
        const float* wp = Wvl + (dy * 3 + dx) * 384 + o0;
        #pragma unroll
        for (int j = 0; j < 8; ++j) a[j] += bf2f((unsigned short)vv[j]) * wp[j];
      }
    }
    char* p = smem + REGA + n * 784 + o0 * 2;
    short8 oc = *(short8*)p;
    short8 s8;
    #pragma unroll
    for (int j = 0; j < 8; ++j)
      s8[j] = (short)f2bf(fmaxf(bf2f((unsigned short)oc[j]) + a[j], 0.f));
    *(short8*)p = s8;
  }
  if (tid < 49) {                    // restore ones-column for P GEMM bias step
    short8 u1 = {0,0,0,0,0,0,0,0};
    u1[0] = (short)f2bf(1.0f);
    *(short8*)(smem + REGA + tid * 784 + 768) = u1;
  }
  __syncthreads();   // b9

  // ---- P GEMM: out = relu_buf @ Wp^T (+bp via k-step 12) --------------------
  {
    f32x4 acc[4][3] = {};
    for (int ks = 0; ks < 13; ++ks) {
      short8 a[4];
      #pragma unroll
      for (int m = 0; m < 4; ++m) {
        int row = m * 16 + llo; row = (row > 48) ? 48 : row;
        a[m] = *(const short8*)(smem + REGA + row * 784 + ks * 64 + lhi * 16);
      }
      #pragma unroll
      for (int n = 0; n < 3; ++n) {
        const int nt = w * 3 + n;
        short8 bfr = *(const short8*)(Wp_p + ((nt * 13 + ks) << 9) + (l << 3));
        #pragma unroll
        for (int m = 0; m < 4; ++m)
          acc[m][n] = __builtin_amdgcn_mfma_f32_16x16x32_bf16(a[m], bfr, acc[m][n], 0, 0, 0);
      }
    }
    float* ob = out + (size_t)b * (NPOS * DIMC);
    #pragma unroll
    for (int n = 0; n < 3; ++n) {
      const int o = (w * 3 + n) * 16 + llo;
      #pragma unroll
      for (int m = 0; m < 4; ++m)
        #pragma unroll
        for (int r = 0; r < 4; ++r) {
          int np = m * 16 + lhi * 4 + r;
          if (np < 49) ob[np * 384 + o] = acc[m][n][r];
        }
    }
  }
}

extern "C" void kernel_launch(void* const* d_in, const int* in_sizes, int n_in,
                              void* d_out, int out_size, void* d_ws, size_t ws_size,
                              hipStream_t stream) {
  const float* x    = (const float*)d_in[0];
  const float* Wq   = (const float*)d_in[1];
  const float* bq   = (const float*)d_in[2];
  const float* Wk   = (const float*)d_in[3];
  const float* bk   = (const float*)d_in[4];
  const float* Wv   = (const float*)d_in[5];
  const float* bv   = (const float*)d_in[6];
  const float* Wvl  = (const float*)d_in[7];
  const float* bvl  = (const float*)d_in[8];
  const float* Wth1 = (const float*)d_in[9];
  const float* bth1 = (const float*)d_in[10];
  const float* Wth2 = (const float*)d_in[11];
  const float* bth2 = (const float*)d_in[12];
  const float* Wp   = (const float*)d_in[13];
  const float* bp   = (const float*)d_in[14];
  unsigned short* Wbf = (unsigned short*)d_ws;   // 1.25 MB of scratch used
  float* out = (float*)d_out;

  hipLaunchKernelGGL(wconv_kernel, dim3(312), dim3(256), 0, stream,
                     Wq, Wk, Wv, Wp, bq, bk, bv, bp, Wbf);
  hipLaunchKernelGGL(attn_fused_kernel, dim3(2048), dim3(512), LDS_BYTES, stream,
                     x, Wvl, bvl, Wth1, bth1, Wth2, bth2, Wbf, out);
}